// Round 5
// baseline (5064.501 us; speedup 1.0000x reference)
//
#include <hip/hip_runtime.h>
#include <hip/hip_bf16.h>

#define NE      4
#define DIM     2048      // model dim: K of gemm1, N of gemm2
#define FF      2048      // per-expert hidden: N of gemm1, K of gemm2
#define NTOK    16384
#define VOCABSZ 100000
#define TPE     (VOCABSZ / NE)
#define SLICE   ((size_t)NE * FF * DIM)   // 16,777,216 elems = 32 MiB bf16
#define NYT     68                        // max 256-row tiles over all experts

typedef __attribute__((ext_vector_type(8))) short bf16x8;
typedef __attribute__((ext_vector_type(4))) float f32x4;

#define GPTR(p) ((const __attribute__((address_space(1))) void*)(p))
#define LPTR(p) ((__attribute__((address_space(3))) void*)(p))
#define MFMA    __builtin_amdgcn_mfma_f32_16x16x32_bf16
#define GLL(g, l) __builtin_amdgcn_global_load_lds(GPTR(g), LPTR(l), 16, 0, 0)

__device__ __forceinline__ unsigned short f2bf(float f) {
  unsigned u = __builtin_bit_cast(unsigned, f);
  u += 0x7fffu + ((u >> 16) & 1u);          // RNE
  return (unsigned short)(u >> 16);
}

__device__ __forceinline__ bf16x8 pack8(float4 a, float4 b) {
  bf16x8 r;
  r[0] = (short)f2bf(a.x); r[1] = (short)f2bf(a.y);
  r[2] = (short)f2bf(a.z); r[3] = (short)f2bf(a.w);
  r[4] = (short)f2bf(b.x); r[5] = (short)f2bf(b.y);
  r[6] = (short)f2bf(b.z); r[7] = (short)f2bf(b.w);
  return r;
}

// meta: [0..3]=counts [4..7]=cursors [8..11]=offsets [12]=ntiles(256)
__global__ void k_init(int* meta) { if (threadIdx.x < 16) meta[threadIdx.x] = 0; }

__global__ void k_assign(const int* __restrict__ tok, int* __restrict__ eid,
                         int* __restrict__ meta) {
  int i = blockIdx.x * 256 + threadIdx.x;
  int t = tok[i];
  t = t < 0 ? 0 : (t >= VOCABSZ ? VOCABSZ - 1 : t);
  int e = t / TPE; if (e > NE - 1) e = NE - 1;
  eid[i] = e;
  atomicAdd(&meta[e], 1);
}

__global__ void k_prefix(int* meta, int* tlist) {
  if (threadIdx.x == 0 && blockIdx.x == 0) {
    int s = 0, n = 0;
    for (int e = 0; e < NE; ++e) {
      meta[8 + e] = s;
      int c = meta[e]; s += c;
      for (int m = 0; m * 256 < c; ++m) tlist[n++] = (e << 16) | m;
    }
    meta[12] = n;
  }
}

__global__ void k_scatter(const int* __restrict__ eid, int* __restrict__ meta,
                          int* __restrict__ perm) {
  int i = blockIdx.x * 256 + threadIdx.x;
  int e = eid[i];
  int pos = meta[8 + e] + atomicAdd(&meta[4 + e], 1);
  perm[pos] = i;
}

// cast Wg, Wu, Wd, X (5 x SLICE fp32) -> contiguous bf16
__global__ void k_cast5(const float* __restrict__ wg, const float* __restrict__ wu,
                        const float* __restrict__ wd, const float* __restrict__ x,
                        unsigned short* __restrict__ dst) {
  int y = blockIdx.y;
  const float* s;
  if (y == 0) s = wg; else if (y == 1) s = wu; else if (y == 2) s = wd;
  else if (y == 3) s = x; else s = x + SLICE;
  unsigned short* d = dst + (size_t)y * SLICE;
  size_t i = ((size_t)blockIdx.x * 256 + threadIdx.x) * 8;
  float4 a = *(const float4*)(s + i);
  float4 b = *(const float4*)(s + i + 4);
  *(bf16x8*)(d + i) = pack8(a, b);
}

// ---------------- GEMM1: Hb = silu(X Wg^T) * (X Wu^T)
// BM=256, dual-B 128(g)+128(u), BK=32, 8 waves (2M x 4N)
// LDS 2 x 32KiB (2 blocks/CU), counted-vmcnt(4) pipeline, never drained mid-loop
__global__ __launch_bounds__(512, 4) void k_gemm1(
    const unsigned short* __restrict__ Xb,
    const unsigned short* __restrict__ Wgb,
    const unsigned short* __restrict__ Wub,
    const int* __restrict__ meta,
    const int* __restrict__ perm,
    const int* __restrict__ tlist,
    unsigned short* __restrict__ Hb)
{
  // XCD-aware remap (NWG = 16*NYT, %8==0)
  int L = blockIdx.y * gridDim.x + blockIdx.x;
  int NWG = gridDim.x * gridDim.y;
  int logical = (L & 7) * (NWG >> 3) + (L >> 3);
  int nt = logical / NYT;
  int ti = logical % NYT;
  if (ti >= meta[12]) return;
  int pk = tlist[ti];
  int e = pk >> 16, mt = pk & 0xffff;
  int cnt = meta[e], base = meta[8 + e];
  int mrows = cnt - mt * 256; if (mrows > 256) mrows = 256;

  // per buffer 32KB: A[256][32] @0, Bg[128][32] @16384, Bu[128][32] @24576
  __shared__ __align__(16) char smem[65536];

  int t = threadIdx.x, lane = t & 63, wid = t >> 6;
  int wm = wid >> 2, wn = wid & 3;

  // staging: thread t -> row ra = t>>2 (within each 128-row group), phys slot p = t&3
  // swizzle: phys p holds logical slot l = p ^ ((row>>1)&3)  (row = tile row)
  int ra  = t >> 2;                                  // 0..127
  int swl = ((t & 3) ^ ((t >> 3) & 3)) * 8;          // source elem offset
  int g0r = mt * 256 + ra;       if (g0r >= cnt) g0r = cnt - 1;
  int g1r = mt * 256 + 128 + ra; if (g1r >= cnt) g1r = cnt - 1;
  const unsigned short* asrc0 = Xb + (size_t)perm[base + g0r] * DIM + swl;
  const unsigned short* asrc1 = Xb + (size_t)perm[base + g1r] * DIM + swl;
  const unsigned short* gsrc  = Wgb + (size_t)e * FF * DIM + (size_t)(nt * 128 + ra) * DIM + swl;
  const unsigned short* usrc  = Wub + (size_t)e * FF * DIM + (size_t)(nt * 128 + ra) * DIM + swl;

  int fr = lane & 15, fc = lane >> 4, fq = lane >> 4;
  int so = (fc ^ ((fr >> 1) & 3)) * 16;              // phys slot byte offset
  int aoff[8], goff[2];
  #pragma unroll
  for (int m = 0; m < 8; ++m) aoff[m] = (wm * 128 + m * 16 + fr) * 64;
  #pragma unroll
  for (int n = 0; n < 2; ++n) goff[n] = (wn * 32 + n * 16 + fr) * 64;

  f32x4 accg[8][2] = {};
  f32x4 accu[8][2] = {};

  auto stage = [&](int b, int k0) {
    char* bb = smem + b * 32768 + wid * 1024;
    GLL(asrc0 + k0, bb);
    GLL(asrc1 + k0, bb + 8192);
    GLL(gsrc  + k0, bb + 16384);
    GLL(usrc  + k0, bb + 24576);
  };

  const int NT2 = DIM / 32;    // 64
  stage(0, 0);
  for (int kt = 0; kt < NT2; ++kt) {
    int b = kt & 1;
    if (kt + 1 < NT2) {
      stage(b ^ 1, (kt + 1) * 32);
      asm volatile("s_waitcnt vmcnt(4)" ::: "memory");
    } else {
      asm volatile("s_waitcnt vmcnt(0)" ::: "memory");
    }
    __builtin_amdgcn_s_barrier();

    const char* Ab = smem + b * 32768;
    const char* Gb = Ab + 16384;
    const char* Ub = Ab + 24576;
    bf16x8 af[8];
    #pragma unroll
    for (int m = 0; m < 8; ++m) af[m] = *(const bf16x8*)(Ab + aoff[m] + so);
    bf16x8 g0 = *(const bf16x8*)(Gb + goff[0] + so);
    bf16x8 g1 = *(const bf16x8*)(Gb + goff[1] + so);
    bf16x8 u0 = *(const bf16x8*)(Ub + goff[0] + so);
    bf16x8 u1 = *(const bf16x8*)(Ub + goff[1] + so);
    __builtin_amdgcn_s_setprio(1);
    #pragma unroll
    for (int m = 0; m < 8; ++m) {
      accg[m][0] = MFMA(af[m], g0, accg[m][0], 0, 0, 0);
      accg[m][1] = MFMA(af[m], g1, accg[m][1], 0, 0, 0);
      accu[m][0] = MFMA(af[m], u0, accu[m][0], 0, 0, 0);
      accu[m][1] = MFMA(af[m], u1, accu[m][1], 0, 0, 0);
    }
    __builtin_amdgcn_s_setprio(0);
    __builtin_amdgcn_s_barrier();
  }

  #pragma unroll
  for (int m = 0; m < 8; ++m) {
    #pragma unroll
    for (int v = 0; v < 4; ++v) {
      int rl = wm * 128 + m * 16 + fq * 4 + v;
      if (rl < mrows) {
        size_t ro = (size_t)(base + mt * 256 + rl) * FF + nt * 128 + wn * 32 + fr;
        float gg0 = accg[m][0][v], uu0 = accu[m][0][v];
        float gg1 = accg[m][1][v], uu1 = accu[m][1][v];
        Hb[ro]      = f2bf(gg0 / (1.0f + __expf(-gg0)) * uu0);
        Hb[ro + 16] = f2bf(gg1 / (1.0f + __expf(-gg1)) * uu1);
      }
    }
  }
}

// ---------------- GEMM2: Out[perm[row]] = Hb Wd^T   (BM=BN=256, BK=32)
__global__ __launch_bounds__(512, 4) void k_gemm2(
    const unsigned short* __restrict__ Hb,
    const unsigned short* __restrict__ Wdb,
    const int* __restrict__ meta,
    const int* __restrict__ perm,
    const int* __restrict__ tlist,
    float* __restrict__ Out)
{
  int L = blockIdx.y * gridDim.x + blockIdx.x;
  int NWG = gridDim.x * gridDim.y;
  int logical = (L & 7) * (NWG >> 3) + (L >> 3);
  int nt = logical / NYT;
  int ti = logical % NYT;
  if (ti >= meta[12]) return;
  int pk = tlist[ti];
  int e = pk >> 16, mt = pk & 0xffff;
  int cnt = meta[e], base = meta[8 + e];
  int mrows = cnt - mt * 256; if (mrows > 256) mrows = 256;

  // per buffer 32KB: A[256][32] @0, B[256][32] @16384
  __shared__ __align__(16) char smem[65536];

  int t = threadIdx.x, lane = t & 63, wid = t >> 6;
  int wm = wid >> 2, wn = wid & 3;

  int ra  = t >> 2;
  int swl = ((t & 3) ^ ((t >> 3) & 3)) * 8;
  int g0r = mt * 256 + ra;       if (g0r >= cnt) g0r = cnt - 1;
  int g1r = mt * 256 + 128 + ra; if (g1r >= cnt) g1r = cnt - 1;
  const unsigned short* asrc0 = Hb + (size_t)(base + g0r) * FF + swl;
  const unsigned short* asrc1 = Hb + (size_t)(base + g1r) * FF + swl;
  const unsigned short* bsrc0 = Wdb + (size_t)e * DIM * FF + (size_t)(nt * 256 + ra) * FF + swl;
  const unsigned short* bsrc1 = Wdb + (size_t)e * DIM * FF + (size_t)(nt * 256 + 128 + ra) * FF + swl;

  int fr = lane & 15, fc = lane >> 4, fq = lane >> 4;
  int so = (fc ^ ((fr >> 1) & 3)) * 16;
  int aoff[8], boff[4];
  #pragma unroll
  for (int m = 0; m < 8; ++m) aoff[m] = (wm * 128 + m * 16 + fr) * 64;
  #pragma unroll
  for (int n = 0; n < 4; ++n) boff[n] = (wn * 64 + n * 16 + fr) * 64;

  f32x4 acc[8][4] = {};

  auto stage = [&](int b, int k0) {
    char* bb = smem + b * 32768 + wid * 1024;
    GLL(asrc0 + k0, bb);
    GLL(asrc1 + k0, bb + 8192);
    GLL(bsrc0 + k0, bb + 16384);
    GLL(bsrc1 + k0, bb + 24576);
  };

  const int NT2 = FF / 32;     // 64
  stage(0, 0);
  for (int kt = 0; kt < NT2; ++kt) {
    int b = kt & 1;
    if (kt + 1 < NT2) {
      stage(b ^ 1, (kt + 1) * 32);
      asm volatile("s_waitcnt vmcnt(4)" ::: "memory");
    } else {
      asm volatile("s_waitcnt vmcnt(0)" ::: "memory");
    }
    __builtin_amdgcn_s_barrier();

    const char* Ab = smem + b * 32768;
    const char* Bb = Ab + 16384;
    bf16x8 af[8], bf[4];
    #pragma unroll
    for (int m = 0; m < 8; ++m) af[m] = *(const bf16x8*)(Ab + aoff[m] + so);
    #pragma unroll
    for (int n = 0; n < 4; ++n) bf[n] = *(const bf16x8*)(Bb + boff[n] + so);
    __builtin_amdgcn_s_setprio(1);
    #pragma unroll
    for (int m = 0; m < 8; ++m) {
      #pragma unroll
      for (int n = 0; n < 4; ++n)
        acc[m][n] = MFMA(af[m], bf[n], acc[m][n], 0, 0, 0);
    }
    __builtin_amdgcn_s_setprio(0);
    __builtin_amdgcn_s_barrier();
  }

  #pragma unroll
  for (int m = 0; m < 8; ++m) {
    #pragma unroll
    for (int v = 0; v < 4; ++v) {
      int rl = wm * 128 + m * 16 + fq * 4 + v;
      if (rl < mrows) {
        int tok = perm[base + mt * 256 + rl];
        float* o = Out + (size_t)tok * DIM + nt * 256 + wn * 64 + fr;
        #pragma unroll
        for (int n = 0; n < 4; ++n)
          o[n * 16] = acc[m][n][v];
      }
    }
  }
}

extern "C" void kernel_launch(void* const* d_in, const int* in_sizes, int n_in,
                              void* d_out, int out_size, void* d_ws, size_t ws_size,
                              hipStream_t stream) {
  (void)in_sizes; (void)n_in; (void)out_size; (void)ws_size;
  const float* X   = (const float*)d_in[0];
  const int*   tok = (const int*)d_in[1];
  const float* Wg  = (const float*)d_in[2];
  const float* Wu  = (const float*)d_in[3];
  const float* Wd  = (const float*)d_in[4];
  float* Out = (float*)d_out;

  char* ws = (char*)d_ws;
  int* meta  = (int*)ws;                      // 16 ints
  int* tlist = (int*)(ws + 64);               // up to ~68 tiles
  int* eid   = (int*)(ws + 2048);             // 16384 ints
  int* perm  = (int*)(ws + 2048 + 65536);     // 16384 ints
  unsigned short* Wbf  = (unsigned short*)(ws + 133120);
  unsigned short* WgBf = Wbf;
  unsigned short* WuBf = Wbf + SLICE;
  unsigned short* WdBf = Wbf + 2 * SLICE;
  unsigned short* Xbf  = Wbf + 3 * SLICE;     // 2 slices (NTOK*DIM)
  unsigned short* Hb   = Wbf + 5 * SLICE;     // NTOK*FF
  // total ws use: 133120 + 5*33554432 + 67108864 = 235,014,144 bytes (~224 MiB)

  k_init   <<<1, 64, 0, stream>>>(meta);
  k_assign <<<NTOK / 256, 256, 0, stream>>>(tok, eid, meta);
  k_prefix <<<1, 64, 0, stream>>>(meta, tlist);
  k_scatter<<<NTOK / 256, 256, 0, stream>>>(eid, meta, perm);
  k_cast5  <<<dim3((unsigned)(SLICE / 2048), 5), 256, 0, stream>>>(Wg, Wu, Wd, X, Wbf);
  k_gemm1  <<<dim3(FF / 128, NYT), 512, 0, stream>>>(Xbf, WgBf, WuBf, meta, perm, tlist, Hb);
  k_gemm2  <<<dim3(DIM / 256, NYT), 512, 0, stream>>>(Hb, WdBf, meta, perm, tlist, Out);
}

// Round 6
// 763.479 us; speedup vs baseline: 6.6335x; 6.6335x over previous
//
#include <hip/hip_runtime.h>
#include <hip/hip_bf16.h>

#define NE      4
#define DIM     2048      // model dim: K of gemm1, N of gemm2
#define FF      2048      // per-expert hidden: N of gemm1, K of gemm2
#define NTOK    16384
#define VOCABSZ 100000
#define TPE     (VOCABSZ / NE)
#define SLICE   ((size_t)NE * FF * DIM)   // 16,777,216 elems = 32 MiB bf16
#define NYT     68                        // max 256-row tiles over all experts

typedef __attribute__((ext_vector_type(8))) short bf16x8;
typedef __attribute__((ext_vector_type(4))) float f32x4;

#define GPTR(p) ((const __attribute__((address_space(1))) void*)(p))
#define LPTR(p) ((__attribute__((address_space(3))) void*)(p))
#define MFMA    __builtin_amdgcn_mfma_f32_16x16x32_bf16
#define GLL(g, l) __builtin_amdgcn_global_load_lds(GPTR(g), LPTR(l), 16, 0, 0)
#define BAR()   __builtin_amdgcn_s_barrier()
#define LGKM0() do { asm volatile("s_waitcnt lgkmcnt(0)" ::: "memory"); \
                     __builtin_amdgcn_sched_barrier(0); } while (0)
#define PRIO(x) __builtin_amdgcn_s_setprio(x)

__device__ __forceinline__ unsigned short f2bf(float f) {
  unsigned u = __builtin_bit_cast(unsigned, f);
  u += 0x7fffu + ((u >> 16) & 1u);          // RNE
  return (unsigned short)(u >> 16);
}

__device__ __forceinline__ bf16x8 pack8(float4 a, float4 b) {
  bf16x8 r;
  r[0] = (short)f2bf(a.x); r[1] = (short)f2bf(a.y);
  r[2] = (short)f2bf(a.z); r[3] = (short)f2bf(a.w);
  r[4] = (short)f2bf(b.x); r[5] = (short)f2bf(b.y);
  r[6] = (short)f2bf(b.z); r[7] = (short)f2bf(b.w);
  return r;
}

// meta: [0..3]=counts [4..7]=cursors [8..11]=offsets [12]=ntiles(256)
__global__ void k_init(int* meta) { if (threadIdx.x < 16) meta[threadIdx.x] = 0; }

__global__ void k_assign(const int* __restrict__ tok, int* __restrict__ eid,
                         int* __restrict__ meta) {
  int i = blockIdx.x * 256 + threadIdx.x;
  int t = tok[i];
  t = t < 0 ? 0 : (t >= VOCABSZ ? VOCABSZ - 1 : t);
  int e = t / TPE; if (e > NE - 1) e = NE - 1;
  eid[i] = e;
  atomicAdd(&meta[e], 1);
}

__global__ void k_prefix(int* meta, int* tlist) {
  if (threadIdx.x == 0 && blockIdx.x == 0) {
    int s = 0, n = 0;
    for (int e = 0; e < NE; ++e) {
      meta[8 + e] = s;
      int c = meta[e]; s += c;
      for (int m = 0; m * 256 < c; ++m) tlist[n++] = (e << 16) | m;
    }
    meta[12] = n;
  }
}

__global__ void k_scatter(const int* __restrict__ eid, int* __restrict__ meta,
                          int* __restrict__ perm) {
  int i = blockIdx.x * 256 + threadIdx.x;
  int e = eid[i];
  int pos = meta[8 + e] + atomicAdd(&meta[4 + e], 1);
  perm[pos] = i;
}

// cast Wg, Wu, Wd, X (5 x SLICE fp32) -> contiguous bf16
__global__ void k_cast5(const float* __restrict__ wg, const float* __restrict__ wu,
                        const float* __restrict__ wd, const float* __restrict__ x,
                        unsigned short* __restrict__ dst) {
  int y = blockIdx.y;
  const float* s;
  if (y == 0) s = wg; else if (y == 1) s = wu; else if (y == 2) s = wd;
  else if (y == 3) s = x; else s = x + SLICE;
  unsigned short* d = dst + (size_t)y * SLICE;
  size_t i = ((size_t)blockIdx.x * 256 + threadIdx.x) * 8;
  float4 a = *(const float4*)(s + i);
  float4 b = *(const float4*)(s + i + 4);
  *(bf16x8*)(d + i) = pack8(a, b);
}

// ---------------- GEMM1: Hb = silu(X Wg^T) * (X Wu^T)
// BM=256, dual-B 128(g)+128(u), BK=64, 8 waves (2M x 4N)
// 4-phase/K-tile pipelined schedule, region-rotated issue, vmcnt(6) at P0/P2 only
__global__ __launch_bounds__(512, 2) void k_gemm1(
    const unsigned short* __restrict__ Xb,
    const unsigned short* __restrict__ Wgb,
    const unsigned short* __restrict__ Wub,
    const int* __restrict__ meta,
    const int* __restrict__ perm,
    const int* __restrict__ tlist,
    unsigned short* __restrict__ Hb)
{
  int L = blockIdx.y * gridDim.x + blockIdx.x;
  int NWG = gridDim.x * gridDim.y;
  int logical = (L & 7) * (NWG >> 3) + (L >> 3);
  int nt = logical / NYT;
  int ti = logical % NYT;
  if (ti >= meta[12]) return;
  int pk = tlist[ti];
  int e = pk >> 16, mt = pk & 0xffff;
  int cnt = meta[e], base = meta[8 + e];
  int mrows = cnt - mt * 256; if (mrows > 256) mrows = 256;

  // per buffer 64KB: A[256][64] @0, G[128][64] @32768, U[128][64] @49152
  __shared__ __align__(16) char smem[131072];

  int t = threadIdx.x, lane = t & 63, wid = t >> 6;
  int wm = wid >> 2, wn = wid & 3;

  // staging: thread t -> row r = t>>3 within each 64-row region, phys slot t&7,
  // source slot pre-swizzled: (t&7) ^ (r&7)
  int r = t >> 3;                              // 0..63
  int swl = ((t & 7) ^ (r & 7)) * 8;           // elem offset
  int gA0 = mt * 256 + r;         if (gA0 >= cnt) gA0 = cnt - 1;
  int gA1 = mt * 256 + 64 + r;    if (gA1 >= cnt) gA1 = cnt - 1;
  int gA2 = mt * 256 + 128 + r;   if (gA2 >= cnt) gA2 = cnt - 1;
  int gA3 = mt * 256 + 192 + r;   if (gA3 >= cnt) gA3 = cnt - 1;
  const unsigned short* pa0 = Xb + (size_t)perm[base + gA0] * DIM + swl;
  const unsigned short* pa1 = Xb + (size_t)perm[base + gA1] * DIM + swl;
  const unsigned short* pa2 = Xb + (size_t)perm[base + gA2] * DIM + swl;
  const unsigned short* pa3 = Xb + (size_t)perm[base + gA3] * DIM + swl;
  size_t wbase = (size_t)e * FF * DIM + (size_t)(nt * 128) * DIM;
  const unsigned short* pg0 = Wgb + wbase + (size_t)r * DIM + swl;
  const unsigned short* pg1 = Wgb + wbase + (size_t)(64 + r) * DIM + swl;
  const unsigned short* pu0 = Wub + wbase + (size_t)r * DIM + swl;
  const unsigned short* pu1 = Wub + wbase + (size_t)(64 + r) * DIM + swl;

  int fr = lane & 15, fc = lane >> 4, fq = lane >> 4;
  int so0 = (fc ^ (fr & 7)) * 16;
  int so1 = ((4 + fc) ^ (fr & 7)) * 16;
  int aoff[8], goff[2];
  #pragma unroll
  for (int m = 0; m < 8; ++m) aoff[m] = (wm * 128 + m * 16 + fr) * 128;
  #pragma unroll
  for (int n = 0; n < 2; ++n) goff[n] = (wn * 32 + n * 16 + fr) * 128;

  f32x4 accg[8][2] = {};
  f32x4 accu[8][2] = {};

  // prologue: tile0 complete + tile1 {A02,G,A13}  (issue order = steady-state order)
  {
    char* a0 = smem + wid * 1024;
    GLL(pa0, a0);              GLL(pa2, a0 + 16384);        // A02(0)
    GLL(pg0, a0 + 32768);      GLL(pg1, a0 + 40960);        // G(0)
    GLL(pa1, a0 + 8192);       GLL(pa3, a0 + 24576);        // A13(0)
    GLL(pu0, a0 + 49152);      GLL(pu1, a0 + 57344);        // U(0)
    char* a1 = smem + 65536 + wid * 1024;
    GLL(pa0 + 64, a1);             GLL(pa2 + 64, a1 + 16384);   // A02(1)
    GLL(pg0 + 64, a1 + 32768);     GLL(pg1 + 64, a1 + 40960);   // G(1)
    GLL(pa1 + 64, a1 + 8192);      GLL(pa3 + 64, a1 + 24576);   // A13(1)
  }
  asm volatile("s_waitcnt vmcnt(6)" ::: "memory");
  BAR();

  const int NT2 = DIM / 64;    // 32
  #pragma unroll 1
  for (int kt = 0; kt < NT2; ++kt) {
    int b = kt & 1;
    const char* Ab = smem + b * 65536;
    const char* Gb = Ab + 32768;
    const char* Ub = Ab + 49152;
    char* cw = smem + b * 65536 + wid * 1024;          // current buf (kt+2 targets)
    char* nw = smem + (b ^ 1) * 65536 + wid * 1024;    // next buf (kt+1 target)
    int k1 = (kt + 1) * 64, k2 = (kt + 2) * 64;
    bf16x8 afr[4][2], g[2][2], u[2][2];

    // ---- P0: m-half0 x g  (ds: 8 A + 4 G; issue U(kt+1); vmcnt)
    #pragma unroll
    for (int m = 0; m < 4; ++m) {
      afr[m][0] = *(const bf16x8*)(Ab + aoff[m] + so0);
      afr[m][1] = *(const bf16x8*)(Ab + aoff[m] + so1);
    }
    #pragma unroll
    for (int n = 0; n < 2; ++n) {
      g[n][0] = *(const bf16x8*)(Gb + goff[n] + so0);
      g[n][1] = *(const bf16x8*)(Gb + goff[n] + so1);
    }
    if (kt + 1 < NT2) { GLL(pu0 + k1, nw + 49152); GLL(pu1 + k1, nw + 57344); }
    if (kt < NT2 - 1) asm volatile("s_waitcnt vmcnt(6)" ::: "memory");
    else              asm volatile("s_waitcnt vmcnt(0)" ::: "memory");
    BAR(); LGKM0(); PRIO(1);
    #pragma unroll
    for (int m = 0; m < 4; ++m) {
      accg[m][0] = MFMA(afr[m][0], g[0][0], accg[m][0], 0, 0, 0);
      accg[m][0] = MFMA(afr[m][1], g[0][1], accg[m][0], 0, 0, 0);
      accg[m][1] = MFMA(afr[m][0], g[1][0], accg[m][1], 0, 0, 0);
      accg[m][1] = MFMA(afr[m][1], g[1][1], accg[m][1], 0, 0, 0);
    }
    PRIO(0); BAR();

    // ---- P1: m-half0 x u  (ds: 4 U; issue A02(kt+2))
    #pragma unroll
    for (int n = 0; n < 2; ++n) {
      u[n][0] = *(const bf16x8*)(Ub + goff[n] + so0);
      u[n][1] = *(const bf16x8*)(Ub + goff[n] + so1);
    }
    if (kt + 2 < NT2) { GLL(pa0 + k2, cw); GLL(pa2 + k2, cw + 16384); }
    BAR(); LGKM0(); PRIO(1);
    #pragma unroll
    for (int m = 0; m < 4; ++m) {
      accu[m][0] = MFMA(afr[m][0], u[0][0], accu[m][0], 0, 0, 0);
      accu[m][0] = MFMA(afr[m][1], u[0][1], accu[m][0], 0, 0, 0);
      accu[m][1] = MFMA(afr[m][0], u[1][0], accu[m][1], 0, 0, 0);
      accu[m][1] = MFMA(afr[m][1], u[1][1], accu[m][1], 0, 0, 0);
    }
    PRIO(0); BAR();

    // ---- P2: m-half1 x g  (ds: 8 A; g held in regs; issue G(kt+2); vmcnt)
    #pragma unroll
    for (int m = 0; m < 4; ++m) {
      afr[m][0] = *(const bf16x8*)(Ab + aoff[4 + m] + so0);
      afr[m][1] = *(const bf16x8*)(Ab + aoff[4 + m] + so1);
    }
    if (kt + 2 < NT2) { GLL(pg0 + k2, cw + 32768); GLL(pg1 + k2, cw + 40960); }
    if (kt + 2 < NT2)      asm volatile("s_waitcnt vmcnt(6)" ::: "memory");
    else if (kt + 1 < NT2) asm volatile("s_waitcnt vmcnt(4)" ::: "memory");
    BAR(); LGKM0(); PRIO(1);
    #pragma unroll
    for (int m = 0; m < 4; ++m) {
      accg[4 + m][0] = MFMA(afr[m][0], g[0][0], accg[4 + m][0], 0, 0, 0);
      accg[4 + m][0] = MFMA(afr[m][1], g[0][1], accg[4 + m][0], 0, 0, 0);
      accg[4 + m][1] = MFMA(afr[m][0], g[1][0], accg[4 + m][1], 0, 0, 0);
      accg[4 + m][1] = MFMA(afr[m][1], g[1][1], accg[4 + m][1], 0, 0, 0);
    }
    PRIO(0); BAR();

    // ---- P3: m-half1 x u  (no ds reads; u + afr held; issue A13(kt+2))
    if (kt + 2 < NT2) { GLL(pa1 + k2, cw + 8192); GLL(pa3 + k2, cw + 24576); }
    PRIO(1);
    #pragma unroll
    for (int m = 0; m < 4; ++m) {
      accu[4 + m][0] = MFMA(afr[m][0], u[0][0], accu[4 + m][0], 0, 0, 0);
      accu[4 + m][0] = MFMA(afr[m][1], u[0][1], accu[4 + m][0], 0, 0, 0);
      accu[4 + m][1] = MFMA(afr[m][0], u[1][0], accu[4 + m][1], 0, 0, 0);
      accu[4 + m][1] = MFMA(afr[m][1], u[1][1], accu[4 + m][1], 0, 0, 0);
    }
    PRIO(0); BAR();
  }

  #pragma unroll
  for (int m = 0; m < 8; ++m) {
    #pragma unroll
    for (int v = 0; v < 4; ++v) {
      int rl = wm * 128 + m * 16 + fq * 4 + v;
      if (rl < mrows) {
        size_t ro = (size_t)(base + mt * 256 + rl) * FF + nt * 128 + wn * 32 + fr;
        float gg0 = accg[m][0][v], uu0 = accu[m][0][v];
        float gg1 = accg[m][1][v], uu1 = accu[m][1][v];
        Hb[ro]      = f2bf(gg0 / (1.0f + __expf(-gg0)) * uu0);
        Hb[ro + 16] = f2bf(gg1 / (1.0f + __expf(-gg1)) * uu1);
      }
    }
  }
}

// ---------------- GEMM2: Out[perm[row]] = Hb Wd^T   (BM=BN=256, BK=64)
__global__ __launch_bounds__(512, 2) void k_gemm2(
    const unsigned short* __restrict__ Hb,
    const unsigned short* __restrict__ Wdb,
    const int* __restrict__ meta,
    const int* __restrict__ perm,
    const int* __restrict__ tlist,
    float* __restrict__ Out)
{
  int L = blockIdx.y * gridDim.x + blockIdx.x;
  int NWG = gridDim.x * gridDim.y;
  int logical = (L & 7) * (NWG >> 3) + (L >> 3);
  int nt = logical / NYT;
  int ti = logical % NYT;
  if (ti >= meta[12]) return;
  int pk = tlist[ti];
  int e = pk >> 16, mt = pk & 0xffff;
  int cnt = meta[e], base = meta[8 + e];
  int mrows = cnt - mt * 256; if (mrows > 256) mrows = 256;

  // per buffer 64KB: A[256][64] @0, B[256][64] @32768
  __shared__ __align__(16) char smem[131072];

  int t = threadIdx.x, lane = t & 63, wid = t >> 6;
  int wm = wid >> 2, wn = wid & 3;

  int r = t >> 3;
  int swl = ((t & 7) ^ (r & 7)) * 8;
  int gA0 = mt * 256 + r;         if (gA0 >= cnt) gA0 = cnt - 1;
  int gA1 = mt * 256 + 64 + r;    if (gA1 >= cnt) gA1 = cnt - 1;
  int gA2 = mt * 256 + 128 + r;   if (gA2 >= cnt) gA2 = cnt - 1;
  int gA3 = mt * 256 + 192 + r;   if (gA3 >= cnt) gA3 = cnt - 1;
  const unsigned short* pa0 = Hb + (size_t)(base + gA0) * FF + swl;
  const unsigned short* pa1 = Hb + (size_t)(base + gA1) * FF + swl;
  const unsigned short* pa2 = Hb + (size_t)(base + gA2) * FF + swl;
  const unsigned short* pa3 = Hb + (size_t)(base + gA3) * FF + swl;
  size_t wbase = (size_t)e * DIM * FF + (size_t)(nt * 256) * FF;
  const unsigned short* pb0 = Wdb + wbase + (size_t)r * FF + swl;
  const unsigned short* pb1 = Wdb + wbase + (size_t)(64 + r) * FF + swl;
  const unsigned short* pb2 = Wdb + wbase + (size_t)(128 + r) * FF + swl;
  const unsigned short* pb3 = Wdb + wbase + (size_t)(192 + r) * FF + swl;

  int fr = lane & 15, fc = lane >> 4, fq = lane >> 4;
  int so0 = (fc ^ (fr & 7)) * 16;
  int so1 = ((4 + fc) ^ (fr & 7)) * 16;
  int aoff[8], boff[4];
  #pragma unroll
  for (int m = 0; m < 8; ++m) aoff[m] = (wm * 128 + m * 16 + fr) * 128;
  #pragma unroll
  for (int n = 0; n < 4; ++n) boff[n] = (wn * 64 + n * 16 + fr) * 128;

  f32x4 acc[8][4] = {};

  {
    char* a0 = smem + wid * 1024;
    GLL(pa0, a0);              GLL(pa2, a0 + 16384);        // A02(0)
    GLL(pb0, a0 + 32768);      GLL(pb1, a0 + 40960);        // B01(0)
    GLL(pb2, a0 + 49152);      GLL(pb3, a0 + 57344);        // B23(0)
    GLL(pa1, a0 + 8192);       GLL(pa3, a0 + 24576);        // A13(0)
    char* a1 = smem + 65536 + wid * 1024;
    GLL(pa0 + 64, a1);             GLL(pa2 + 64, a1 + 16384);   // A02(1)
    GLL(pb0 + 64, a1 + 32768);     GLL(pb1 + 64, a1 + 40960);   // B01(1)
    GLL(pb2 + 64, a1 + 49152);     GLL(pb3 + 64, a1 + 57344);   // B23(1)
  }
  asm volatile("s_waitcnt vmcnt(6)" ::: "memory");
  BAR();

  const int NT2 = FF / 64;     // 32
  #pragma unroll 1
  for (int kt = 0; kt < NT2; ++kt) {
    int b = kt & 1;
    const char* Ab = smem + b * 65536;
    const char* Bb = Ab + 32768;
    char* cw = smem + b * 65536 + wid * 1024;
    char* nw = smem + (b ^ 1) * 65536 + wid * 1024;
    int k1 = (kt + 1) * 64, k2 = (kt + 2) * 64;
    bf16x8 afr[4][2], b01[2][2], b23[2][2];

    // ---- P0: m-half0 x n01  (ds: 8 A + 4 B; issue A13(kt+1); vmcnt)
    #pragma unroll
    for (int m = 0; m < 4; ++m) {
      afr[m][0] = *(const bf16x8*)(Ab + aoff[m] + so0);
      afr[m][1] = *(const bf16x8*)(Ab + aoff[m] + so1);
    }
    #pragma unroll
    for (int n = 0; n < 2; ++n) {
      b01[n][0] = *(const bf16x8*)(Bb + boff[n] + so0);
      b01[n][1] = *(const bf16x8*)(Bb + boff[n] + so1);
    }
    if (kt + 1 < NT2) { GLL(pa1 + k1, nw + 8192); GLL(pa3 + k1, nw + 24576); }
    if (kt < NT2 - 1) asm volatile("s_waitcnt vmcnt(6)" ::: "memory");
    else              asm volatile("s_waitcnt vmcnt(0)" ::: "memory");
    BAR(); LGKM0(); PRIO(1);
    #pragma unroll
    for (int m = 0; m < 4; ++m) {
      acc[m][0] = MFMA(afr[m][0], b01[0][0], acc[m][0], 0, 0, 0);
      acc[m][0] = MFMA(afr[m][1], b01[0][1], acc[m][0], 0, 0, 0);
      acc[m][1] = MFMA(afr[m][0], b01[1][0], acc[m][1], 0, 0, 0);
      acc[m][1] = MFMA(afr[m][1], b01[1][1], acc[m][1], 0, 0, 0);
    }
    PRIO(0); BAR();

    // ---- P1: m-half0 x n23  (ds: 4 B; issue A02(kt+2))
    #pragma unroll
    for (int n = 0; n < 2; ++n) {
      b23[n][0] = *(const bf16x8*)(Bb + boff[2 + n] + so0);
      b23[n][1] = *(const bf16x8*)(Bb + boff[2 + n] + so1);
    }
    if (kt + 2 < NT2) { GLL(pa0 + k2, cw); GLL(pa2 + k2, cw + 16384); }
    BAR(); LGKM0(); PRIO(1);
    #pragma unroll
    for (int m = 0; m < 4; ++m) {
      acc[m][2] = MFMA(afr[m][0], b23[0][0], acc[m][2], 0, 0, 0);
      acc[m][2] = MFMA(afr[m][1], b23[0][1], acc[m][2], 0, 0, 0);
      acc[m][3] = MFMA(afr[m][0], b23[1][0], acc[m][3], 0, 0, 0);
      acc[m][3] = MFMA(afr[m][1], b23[1][1], acc[m][3], 0, 0, 0);
    }
    PRIO(0); BAR();

    // ---- P2: m-half1 x n01  (ds: 8 A; b01 held; issue B01(kt+2); vmcnt)
    #pragma unroll
    for (int m = 0; m < 4; ++m) {
      afr[m][0] = *(const bf16x8*)(Ab + aoff[4 + m] + so0);
      afr[m][1] = *(const bf16x8*)(Ab + aoff[4 + m] + so1);
    }
    if (kt + 2 < NT2) { GLL(pb0 + k2, cw + 32768); GLL(pb1 + k2, cw + 40960); }
    if (kt + 2 < NT2)      asm volatile("s_waitcnt vmcnt(6)" ::: "memory");
    else if (kt + 1 < NT2) asm volatile("s_waitcnt vmcnt(2)" ::: "memory");
    BAR(); LGKM0(); PRIO(1);
    #pragma unroll
    for (int m = 0; m < 4; ++m) {
      acc[4 + m][0] = MFMA(afr[m][0], b01[0][0], acc[4 + m][0], 0, 0, 0);
      acc[4 + m][0] = MFMA(afr[m][1], b01[0][1], acc[4 + m][0], 0, 0, 0);
      acc[4 + m][1] = MFMA(afr[m][0], b01[1][0], acc[4 + m][1], 0, 0, 0);
      acc[4 + m][1] = MFMA(afr[m][1], b01[1][1], acc[4 + m][1], 0, 0, 0);
    }
    PRIO(0); BAR();

    // ---- P3: m-half1 x n23  (no ds; issue B23(kt+2))
    if (kt + 2 < NT2) { GLL(pb2 + k2, cw + 49152); GLL(pb3 + k2, cw + 57344); }
    PRIO(1);
    #pragma unroll
    for (int m = 0; m < 4; ++m) {
      acc[4 + m][2] = MFMA(afr[m][0], b23[0][0], acc[4 + m][2], 0, 0, 0);
      acc[4 + m][2] = MFMA(afr[m][1], b23[0][1], acc[4 + m][2], 0, 0, 0);
      acc[4 + m][3] = MFMA(afr[m][0], b23[1][0], acc[4 + m][3], 0, 0, 0);
      acc[4 + m][3] = MFMA(afr[m][1], b23[1][1], acc[4 + m][3], 0, 0, 0);
    }
    PRIO(0); BAR();
  }

  #pragma unroll
  for (int m = 0; m < 8; ++m) {
    #pragma unroll
    for (int v = 0; v < 4; ++v) {
      int rl = wm * 128 + m * 16 + fq * 4 + v;
      if (rl < mrows) {
        int tok = perm[base + mt * 256 + rl];
        float* o = Out + (size_t)tok * DIM + nt * 256 + wn * 64 + fr;
        #pragma unroll
        for (int n = 0; n < 4; ++n)
          o[n * 16] = acc[m][n][v];
      }
    }
  }
}

extern "C" void kernel_launch(void* const* d_in, const int* in_sizes, int n_in,
                              void* d_out, int out_size, void* d_ws, size_t ws_size,
                              hipStream_t stream) {
  (void)in_sizes; (void)n_in; (void)out_size; (void)ws_size;
  const float* X   = (const float*)d_in[0];
  const int*   tok = (const int*)d_in[1];
  const float* Wg  = (const float*)d_in[2];
  const float* Wu  = (const float*)d_in[3];
  const float* Wd  = (const float*)d_in[4];
  float* Out = (float*)d_out;

  char* ws = (char*)d_ws;
  int* meta  = (int*)ws;                      // 16 ints
  int* tlist = (int*)(ws + 64);               // up to ~68 tiles
  int* eid   = (int*)(ws + 2048);             // 16384 ints
  int* perm  = (int*)(ws + 2048 + 65536);     // 16384 ints
  unsigned short* Wbf  = (unsigned short*)(ws + 133120);
  unsigned short* WgBf = Wbf;
  unsigned short* WuBf = Wbf + SLICE;
  unsigned short* WdBf = Wbf + 2 * SLICE;
  unsigned short* Xbf  = Wbf + 3 * SLICE;     // 2 slices (NTOK*DIM)
  unsigned short* Hb   = Wbf + 5 * SLICE;     // NTOK*FF
  // total ws use: 133120 + 5*33554432 + 67108864 = 235,014,144 bytes (~224 MiB)

  k_init   <<<1, 64, 0, stream>>>(meta);
  k_assign <<<NTOK / 256, 256, 0, stream>>>(tok, eid, meta);
  k_prefix <<<1, 64, 0, stream>>>(meta, tlist);
  k_scatter<<<NTOK / 256, 256, 0, stream>>>(eid, meta, perm);
  k_cast5  <<<dim3((unsigned)(SLICE / 2048), 5), 256, 0, stream>>>(Wg, Wu, Wd, X, Wbf);
  k_gemm1  <<<dim3(FF / 128, NYT), 512, 0, stream>>>(Xbf, WgBf, WuBf, meta, perm, tlist, Hb);
  k_gemm2  <<<dim3(DIM / 256, NYT), 512, 0, stream>>>(Hb, WdBf, meta, perm, tlist, Out);
}

// Round 7
// 762.186 us; speedup vs baseline: 6.6447x; 1.0017x over previous
//
#include <hip/hip_runtime.h>
#include <hip/hip_bf16.h>

#define NE      4
#define DIM     2048      // model dim: K of gemm1, N of gemm2
#define FF      2048      // per-expert hidden: N of gemm1, K of gemm2
#define NTOK    16384
#define VOCABSZ 100000
#define TPE     (VOCABSZ / NE)
#define SLICE   ((size_t)NE * FF * DIM)   // 16,777,216 elems = 32 MiB bf16
#define NYT     68                        // max 256-row tiles over all experts

typedef __attribute__((ext_vector_type(8))) short bf16x8;
typedef __attribute__((ext_vector_type(4))) float f32x4;

#define GPTR(p) ((const __attribute__((address_space(1))) void*)(p))
#define LPTR(p) ((__attribute__((address_space(3))) void*)(p))
#define MFMA    __builtin_amdgcn_mfma_f32_16x16x32_bf16
#define GLL(g, l) __builtin_amdgcn_global_load_lds(GPTR(g), LPTR(l), 16, 0, 0)
#define BAR()   __builtin_amdgcn_s_barrier()
#define PRIO(x) __builtin_amdgcn_s_setprio(x)

__device__ __forceinline__ unsigned short f2bf(float f) {
  unsigned u = __builtin_bit_cast(unsigned, f);
  u += 0x7fffu + ((u >> 16) & 1u);          // RNE
  return (unsigned short)(u >> 16);
}

__device__ __forceinline__ bf16x8 pack8(float4 a, float4 b) {
  bf16x8 r;
  r[0] = (short)f2bf(a.x); r[1] = (short)f2bf(a.y);
  r[2] = (short)f2bf(a.z); r[3] = (short)f2bf(a.w);
  r[4] = (short)f2bf(b.x); r[5] = (short)f2bf(b.y);
  r[6] = (short)f2bf(b.z); r[7] = (short)f2bf(b.w);
  return r;
}

// meta: [0..3]=counts [4..7]=cursors [8..11]=offsets [12]=ntiles(256)
__global__ void k_init(int* meta) { if (threadIdx.x < 16) meta[threadIdx.x] = 0; }

__global__ void k_assign(const int* __restrict__ tok, int* __restrict__ eid,
                         int* __restrict__ meta) {
  int i = blockIdx.x * 256 + threadIdx.x;
  int t = tok[i];
  t = t < 0 ? 0 : (t >= VOCABSZ ? VOCABSZ - 1 : t);
  int e = t / TPE; if (e > NE - 1) e = NE - 1;
  eid[i] = e;
  atomicAdd(&meta[e], 1);
}

__global__ void k_prefix(int* meta, int* tlist) {
  if (threadIdx.x == 0 && blockIdx.x == 0) {
    int s = 0, n = 0;
    for (int e = 0; e < NE; ++e) {
      meta[8 + e] = s;
      int c = meta[e]; s += c;
      for (int m = 0; m * 256 < c; ++m) tlist[n++] = (e << 16) | m;
    }
    meta[12] = n;
  }
}

__global__ void k_scatter(const int* __restrict__ eid, int* __restrict__ meta,
                          int* __restrict__ perm, int* __restrict__ inv) {
  int i = blockIdx.x * 256 + threadIdx.x;
  int e = eid[i];
  int pos = meta[8 + e] + atomicAdd(&meta[4 + e], 1);
  perm[pos] = i;
  inv[i] = pos;
}

// cast Wg, Wu, Wd (linear) and X (scatter into expert-sorted Xs) fp32 -> bf16
__global__ void k_cast5(const float* __restrict__ wg, const float* __restrict__ wu,
                        const float* __restrict__ wd, const float* __restrict__ x,
                        const int* __restrict__ inv, unsigned short* __restrict__ dst) {
  int y = blockIdx.y;
  size_t i = ((size_t)blockIdx.x * 256 + threadIdx.x) * 8;
  if (y < 3) {
    const float* s = (y == 0 ? wg : (y == 1 ? wu : wd)) + i;
    unsigned short* d = dst + (size_t)y * SLICE + i;
    float4 a = *(const float4*)(s);
    float4 b = *(const float4*)(s + 4);
    *(bf16x8*)d = pack8(a, b);
  } else {
    size_t ig = (size_t)(y - 3) * SLICE + i;        // element index into X
    int token = (int)(ig >> 11);
    int col   = (int)(ig & 2047);
    const float* s = x + ig;
    unsigned short* d = dst + 3 * SLICE + (size_t)inv[token] * 2048 + col;
    float4 a = *(const float4*)(s);
    float4 b = *(const float4*)(s + 4);
    *(bf16x8*)d = pack8(a, b);
  }
}

// ---------------- GEMM1: Hb = silu(Xs Wg^T) * (Xs Wu^T), Xs expert-sorted
// BM=256, dual-B 128(g)+128(u), BK=64, 8 waves (2M x 4N)
// A-major XCD grouping: contiguous logicals = same m-tile (A L2-hot), nt varies
__global__ __launch_bounds__(512, 2) void k_gemm1(
    const unsigned short* __restrict__ Xs,
    const unsigned short* __restrict__ Wgb,
    const unsigned short* __restrict__ Wub,
    const int* __restrict__ meta,
    const int* __restrict__ tlist,
    unsigned short* __restrict__ Hb)
{
  int L = blockIdx.y * gridDim.x + blockIdx.x;
  int NWG = gridDim.x * gridDim.y;          // 16*NYT, %8==0
  int logical = (L & 7) * (NWG >> 3) + (L >> 3);
  int ti = logical >> 4;                    // A-major: same ti for 16 consecutive
  int nt = logical & 15;
  if (ti >= meta[12]) return;
  int pk = tlist[ti];
  int e = pk >> 16, mt = pk & 0xffff;
  int cnt = meta[e], base = meta[8 + e];
  int mrows = cnt - mt * 256; if (mrows > 256) mrows = 256;

  // per buffer 64KB: A[256][64] @0, G[128][64] @32768, U[128][64] @49152
  __shared__ __align__(16) char smem[131072];

  int t = threadIdx.x, lane = t & 63, wid = t >> 6;
  int wm = wid >> 2, wn = wid & 3;

  // staging: thread t -> row r = t>>3 in each 64-row region, phys slot t&7,
  // pre-swizzled source slot (t&7)^(r&7)
  int r = t >> 3;                              // 0..63
  int swl = ((t & 7) ^ (r & 7)) * 8;           // elem offset
  int gA0 = mt * 256 + r;         if (gA0 >= cnt) gA0 = cnt - 1;
  int gA1 = mt * 256 + 64 + r;    if (gA1 >= cnt) gA1 = cnt - 1;
  int gA2 = mt * 256 + 128 + r;   if (gA2 >= cnt) gA2 = cnt - 1;
  int gA3 = mt * 256 + 192 + r;   if (gA3 >= cnt) gA3 = cnt - 1;
  const unsigned short* pa0 = Xs + (size_t)(base + gA0) * DIM + swl;
  const unsigned short* pa1 = Xs + (size_t)(base + gA1) * DIM + swl;
  const unsigned short* pa2 = Xs + (size_t)(base + gA2) * DIM + swl;
  const unsigned short* pa3 = Xs + (size_t)(base + gA3) * DIM + swl;
  size_t wbase = (size_t)e * FF * DIM + (size_t)(nt * 128) * DIM;
  const unsigned short* pg0 = Wgb + wbase + (size_t)r * DIM + swl;
  const unsigned short* pg1 = Wgb + wbase + (size_t)(64 + r) * DIM + swl;
  const unsigned short* pu0 = Wub + wbase + (size_t)r * DIM + swl;
  const unsigned short* pu1 = Wub + wbase + (size_t)(64 + r) * DIM + swl;

  int fr = lane & 15, fc = lane >> 4, fq = lane >> 4;
  int so0 = (fc ^ (fr & 7)) * 16;
  int so1 = ((4 + fc) ^ (fr & 7)) * 16;
  int aoff[8], goff[2];
  #pragma unroll
  for (int m = 0; m < 8; ++m) aoff[m] = (wm * 128 + m * 16 + fr) * 128;
  #pragma unroll
  for (int n = 0; n < 2; ++n) goff[n] = (wn * 32 + n * 16 + fr) * 128;

  f32x4 accg[8][2] = {};
  f32x4 accu[8][2] = {};

  // prologue: tile0 complete + tile1 {A02,G,A13}
  {
    char* a0 = smem + wid * 1024;
    GLL(pa0, a0);              GLL(pa2, a0 + 16384);
    GLL(pg0, a0 + 32768);      GLL(pg1, a0 + 40960);
    GLL(pa1, a0 + 8192);       GLL(pa3, a0 + 24576);
    GLL(pu0, a0 + 49152);      GLL(pu1, a0 + 57344);
    char* a1 = smem + 65536 + wid * 1024;
    GLL(pa0 + 64, a1);             GLL(pa2 + 64, a1 + 16384);
    GLL(pg0 + 64, a1 + 32768);     GLL(pg1 + 64, a1 + 40960);
    GLL(pa1 + 64, a1 + 8192);      GLL(pa3 + 64, a1 + 24576);
  }
  asm volatile("s_waitcnt vmcnt(6)" ::: "memory");
  BAR();

  const int NT2 = DIM / 64;    // 32
  #pragma unroll 1
  for (int kt = 0; kt < NT2; ++kt) {
    int b = kt & 1;
    const char* Ab = smem + b * 65536;
    const char* Gb = Ab + 32768;
    const char* Ub = Ab + 49152;
    char* cw = smem + b * 65536 + wid * 1024;
    char* nw = smem + (b ^ 1) * 65536 + wid * 1024;
    int k1 = (kt + 1) * 64, k2 = (kt + 2) * 64;
    bf16x8 afr[4][2], g[2][2], u[2][2];

    // ---- P0: m-half0 x g
    #pragma unroll
    for (int m = 0; m < 4; ++m) {
      afr[m][0] = *(const bf16x8*)(Ab + aoff[m] + so0);
      afr[m][1] = *(const bf16x8*)(Ab + aoff[m] + so1);
    }
    #pragma unroll
    for (int n = 0; n < 2; ++n) {
      g[n][0] = *(const bf16x8*)(Gb + goff[n] + so0);
      g[n][1] = *(const bf16x8*)(Gb + goff[n] + so1);
    }
    if (kt + 1 < NT2) { GLL(pu0 + k1, nw + 49152); GLL(pu1 + k1, nw + 57344); }
    if (kt < NT2 - 1) asm volatile("s_waitcnt vmcnt(6)" ::: "memory");
    else              asm volatile("s_waitcnt vmcnt(0)" ::: "memory");
    BAR(); PRIO(1);
    #pragma unroll
    for (int m = 0; m < 4; ++m) {
      accg[m][0] = MFMA(afr[m][0], g[0][0], accg[m][0], 0, 0, 0);
      accg[m][0] = MFMA(afr[m][1], g[0][1], accg[m][0], 0, 0, 0);
      accg[m][1] = MFMA(afr[m][0], g[1][0], accg[m][1], 0, 0, 0);
      accg[m][1] = MFMA(afr[m][1], g[1][1], accg[m][1], 0, 0, 0);
    }
    PRIO(0); BAR();

    // ---- P1: m-half0 x u
    #pragma unroll
    for (int n = 0; n < 2; ++n) {
      u[n][0] = *(const bf16x8*)(Ub + goff[n] + so0);
      u[n][1] = *(const bf16x8*)(Ub + goff[n] + so1);
    }
    if (kt + 2 < NT2) { GLL(pa0 + k2, cw); GLL(pa2 + k2, cw + 16384); }
    BAR(); PRIO(1);
    #pragma unroll
    for (int m = 0; m < 4; ++m) {
      accu[m][0] = MFMA(afr[m][0], u[0][0], accu[m][0], 0, 0, 0);
      accu[m][0] = MFMA(afr[m][1], u[0][1], accu[m][0], 0, 0, 0);
      accu[m][1] = MFMA(afr[m][0], u[1][0], accu[m][1], 0, 0, 0);
      accu[m][1] = MFMA(afr[m][1], u[1][1], accu[m][1], 0, 0, 0);
    }
    PRIO(0); BAR();

    // ---- P2: m-half1 x g  (g held in regs)
    #pragma unroll
    for (int m = 0; m < 4; ++m) {
      afr[m][0] = *(const bf16x8*)(Ab + aoff[4 + m] + so0);
      afr[m][1] = *(const bf16x8*)(Ab + aoff[4 + m] + so1);
    }
    if (kt + 2 < NT2) { GLL(pg0 + k2, cw + 32768); GLL(pg1 + k2, cw + 40960); }
    if (kt + 2 < NT2)      asm volatile("s_waitcnt vmcnt(6)" ::: "memory");
    else if (kt + 1 < NT2) asm volatile("s_waitcnt vmcnt(4)" ::: "memory");
    BAR(); PRIO(1);
    #pragma unroll
    for (int m = 0; m < 4; ++m) {
      accg[4 + m][0] = MFMA(afr[m][0], g[0][0], accg[4 + m][0], 0, 0, 0);
      accg[4 + m][0] = MFMA(afr[m][1], g[0][1], accg[4 + m][0], 0, 0, 0);
      accg[4 + m][1] = MFMA(afr[m][0], g[1][0], accg[4 + m][1], 0, 0, 0);
      accg[4 + m][1] = MFMA(afr[m][1], g[1][1], accg[4 + m][1], 0, 0, 0);
    }
    PRIO(0); BAR();

    // ---- P3: m-half1 x u  (no ds reads)
    if (kt + 2 < NT2) { GLL(pa1 + k2, cw + 8192); GLL(pa3 + k2, cw + 24576); }
    PRIO(1);
    #pragma unroll
    for (int m = 0; m < 4; ++m) {
      accu[4 + m][0] = MFMA(afr[m][0], u[0][0], accu[4 + m][0], 0, 0, 0);
      accu[4 + m][0] = MFMA(afr[m][1], u[0][1], accu[4 + m][0], 0, 0, 0);
      accu[4 + m][1] = MFMA(afr[m][0], u[1][0], accu[4 + m][1], 0, 0, 0);
      accu[4 + m][1] = MFMA(afr[m][1], u[1][1], accu[4 + m][1], 0, 0, 0);
    }
    PRIO(0); BAR();
  }

  #pragma unroll
  for (int m = 0; m < 8; ++m) {
    #pragma unroll
    for (int v = 0; v < 4; ++v) {
      int rl = wm * 128 + m * 16 + fq * 4 + v;
      if (rl < mrows) {
        size_t ro = (size_t)(base + mt * 256 + rl) * FF + nt * 128 + wn * 32 + fr;
        float gg0 = accg[m][0][v], uu0 = accu[m][0][v];
        float gg1 = accg[m][1][v], uu1 = accu[m][1][v];
        Hb[ro]      = f2bf(gg0 / (1.0f + __expf(-gg0)) * uu0);
        Hb[ro + 16] = f2bf(gg1 / (1.0f + __expf(-gg1)) * uu1);
      }
    }
  }
}

// ---------------- GEMM2: Out[perm[row]] = Hb Wd^T   (BM=BN=256, BK=64)
__global__ __launch_bounds__(512, 2) void k_gemm2(
    const unsigned short* __restrict__ Hb,
    const unsigned short* __restrict__ Wdb,
    const int* __restrict__ meta,
    const int* __restrict__ perm,
    const int* __restrict__ tlist,
    float* __restrict__ Out)
{
  int L = blockIdx.y * gridDim.x + blockIdx.x;
  int NWG = gridDim.x * gridDim.y;          // 8*NYT
  int logical = (L & 7) * (NWG >> 3) + (L >> 3);
  int ti = logical >> 3;                    // A-major grouping
  int nt = logical & 7;
  if (ti >= meta[12]) return;
  int pk = tlist[ti];
  int e = pk >> 16, mt = pk & 0xffff;
  int cnt = meta[e], base = meta[8 + e];
  int mrows = cnt - mt * 256; if (mrows > 256) mrows = 256;

  // per buffer 64KB: A[256][64] @0, B[256][64] @32768
  __shared__ __align__(16) char smem[131072];

  int t = threadIdx.x, lane = t & 63, wid = t >> 6;
  int wm = wid >> 2, wn = wid & 3;

  int r = t >> 3;
  int swl = ((t & 7) ^ (r & 7)) * 8;
  int gA0 = mt * 256 + r;         if (gA0 >= cnt) gA0 = cnt - 1;
  int gA1 = mt * 256 + 64 + r;    if (gA1 >= cnt) gA1 = cnt - 1;
  int gA2 = mt * 256 + 128 + r;   if (gA2 >= cnt) gA2 = cnt - 1;
  int gA3 = mt * 256 + 192 + r;   if (gA3 >= cnt) gA3 = cnt - 1;
  const unsigned short* pa0 = Hb + (size_t)(base + gA0) * FF + swl;
  const unsigned short* pa1 = Hb + (size_t)(base + gA1) * FF + swl;
  const unsigned short* pa2 = Hb + (size_t)(base + gA2) * FF + swl;
  const unsigned short* pa3 = Hb + (size_t)(base + gA3) * FF + swl;
  size_t wbase = (size_t)e * DIM * FF + (size_t)(nt * 256) * FF;
  const unsigned short* pb0 = Wdb + wbase + (size_t)r * FF + swl;
  const unsigned short* pb1 = Wdb + wbase + (size_t)(64 + r) * FF + swl;
  const unsigned short* pb2 = Wdb + wbase + (size_t)(128 + r) * FF + swl;
  const unsigned short* pb3 = Wdb + wbase + (size_t)(192 + r) * FF + swl;

  int fr = lane & 15, fc = lane >> 4, fq = lane >> 4;
  int so0 = (fc ^ (fr & 7)) * 16;
  int so1 = ((4 + fc) ^ (fr & 7)) * 16;
  int aoff[8], boff[4];
  #pragma unroll
  for (int m = 0; m < 8; ++m) aoff[m] = (wm * 128 + m * 16 + fr) * 128;
  #pragma unroll
  for (int n = 0; n < 4; ++n) boff[n] = (wn * 64 + n * 16 + fr) * 128;

  f32x4 acc[8][4] = {};

  {
    char* a0 = smem + wid * 1024;
    GLL(pa0, a0);              GLL(pa2, a0 + 16384);
    GLL(pb0, a0 + 32768);      GLL(pb1, a0 + 40960);
    GLL(pb2, a0 + 49152);      GLL(pb3, a0 + 57344);
    GLL(pa1, a0 + 8192);       GLL(pa3, a0 + 24576);
    char* a1 = smem + 65536 + wid * 1024;
    GLL(pa0 + 64, a1);             GLL(pa2 + 64, a1 + 16384);
    GLL(pb0 + 64, a1 + 32768);     GLL(pb1 + 64, a1 + 40960);
    GLL(pb2 + 64, a1 + 49152);     GLL(pb3 + 64, a1 + 57344);
  }
  asm volatile("s_waitcnt vmcnt(6)" ::: "memory");
  BAR();

  const int NT2 = FF / 64;     // 32
  #pragma unroll 1
  for (int kt = 0; kt < NT2; ++kt) {
    int b = kt & 1;
    const char* Ab = smem + b * 65536;
    const char* Bb = Ab + 32768;
    char* cw = smem + b * 65536 + wid * 1024;
    char* nw = smem + (b ^ 1) * 65536 + wid * 1024;
    int k1 = (kt + 1) * 64, k2 = (kt + 2) * 64;
    bf16x8 afr[4][2], b01[2][2], b23[2][2];

    // ---- P0: m-half0 x n01
    #pragma unroll
    for (int m = 0; m < 4; ++m) {
      afr[m][0] = *(const bf16x8*)(Ab + aoff[m] + so0);
      afr[m][1] = *(const bf16x8*)(Ab + aoff[m] + so1);
    }
    #pragma unroll
    for (int n = 0; n < 2; ++n) {
      b01[n][0] = *(const bf16x8*)(Bb + boff[n] + so0);
      b01[n][1] = *(const bf16x8*)(Bb + boff[n] + so1);
    }
    if (kt + 1 < NT2) { GLL(pa1 + k1, nw + 8192); GLL(pa3 + k1, nw + 24576); }
    if (kt < NT2 - 1) asm volatile("s_waitcnt vmcnt(6)" ::: "memory");
    else              asm volatile("s_waitcnt vmcnt(0)" ::: "memory");
    BAR(); PRIO(1);
    #pragma unroll
    for (int m = 0; m < 4; ++m) {
      acc[m][0] = MFMA(afr[m][0], b01[0][0], acc[m][0], 0, 0, 0);
      acc[m][0] = MFMA(afr[m][1], b01[0][1], acc[m][0], 0, 0, 0);
      acc[m][1] = MFMA(afr[m][0], b01[1][0], acc[m][1], 0, 0, 0);
      acc[m][1] = MFMA(afr[m][1], b01[1][1], acc[m][1], 0, 0, 0);
    }
    PRIO(0); BAR();

    // ---- P1: m-half0 x n23
    #pragma unroll
    for (int n = 0; n < 2; ++n) {
      b23[n][0] = *(const bf16x8*)(Bb + boff[2 + n] + so0);
      b23[n][1] = *(const bf16x8*)(Bb + boff[2 + n] + so1);
    }
    if (kt + 2 < NT2) { GLL(pa0 + k2, cw); GLL(pa2 + k2, cw + 16384); }
    BAR(); PRIO(1);
    #pragma unroll
    for (int m = 0; m < 4; ++m) {
      acc[m][2] = MFMA(afr[m][0], b23[0][0], acc[m][2], 0, 0, 0);
      acc[m][2] = MFMA(afr[m][1], b23[0][1], acc[m][2], 0, 0, 0);
      acc[m][3] = MFMA(afr[m][0], b23[1][0], acc[m][3], 0, 0, 0);
      acc[m][3] = MFMA(afr[m][1], b23[1][1], acc[m][3], 0, 0, 0);
    }
    PRIO(0); BAR();

    // ---- P2: m-half1 x n01  (b01 held)
    #pragma unroll
    for (int m = 0; m < 4; ++m) {
      afr[m][0] = *(const bf16x8*)(Ab + aoff[4 + m] + so0);
      afr[m][1] = *(const bf16x8*)(Ab + aoff[4 + m] + so1);
    }
    if (kt + 2 < NT2) { GLL(pb0 + k2, cw + 32768); GLL(pb1 + k2, cw + 40960); }
    if (kt + 2 < NT2)      asm volatile("s_waitcnt vmcnt(6)" ::: "memory");
    else if (kt + 1 < NT2) asm volatile("s_waitcnt vmcnt(2)" ::: "memory");
    BAR(); PRIO(1);
    #pragma unroll
    for (int m = 0; m < 4; ++m) {
      acc[4 + m][0] = MFMA(afr[m][0], b01[0][0], acc[4 + m][0], 0, 0, 0);
      acc[4 + m][0] = MFMA(afr[m][1], b01[0][1], acc[4 + m][0], 0, 0, 0);
      acc[4 + m][1] = MFMA(afr[m][0], b01[1][0], acc[4 + m][1], 0, 0, 0);
      acc[4 + m][1] = MFMA(afr[m][1], b01[1][1], acc[4 + m][1], 0, 0, 0);
    }
    PRIO(0); BAR();

    // ---- P3: m-half1 x n23
    if (kt + 2 < NT2) { GLL(pb2 + k2, cw + 49152); GLL(pb3 + k2, cw + 57344); }
    PRIO(1);
    #pragma unroll
    for (int m = 0; m < 4; ++m) {
      acc[4 + m][2] = MFMA(afr[m][0], b23[0][0], acc[4 + m][2], 0, 0, 0);
      acc[4 + m][2] = MFMA(afr[m][1], b23[0][1], acc[4 + m][2], 0, 0, 0);
      acc[4 + m][3] = MFMA(afr[m][0], b23[1][0], acc[4 + m][3], 0, 0, 0);
      acc[4 + m][3] = MFMA(afr[m][1], b23[1][1], acc[4 + m][3], 0, 0, 0);
    }
    PRIO(0); BAR();
  }

  #pragma unroll
  for (int m = 0; m < 8; ++m) {
    #pragma unroll
    for (int v = 0; v < 4; ++v) {
      int rl = wm * 128 + m * 16 + fq * 4 + v;
      if (rl < mrows) {
        int tok = perm[base + mt * 256 + rl];
        float* o = Out + (size_t)tok * DIM + nt * 256 + wn * 64 + fr;
        #pragma unroll
        for (int n = 0; n < 4; ++n)
          o[n * 16] = acc[m][n][v];
      }
    }
  }
}

extern "C" void kernel_launch(void* const* d_in, const int* in_sizes, int n_in,
                              void* d_out, int out_size, void* d_ws, size_t ws_size,
                              hipStream_t stream) {
  (void)in_sizes; (void)n_in; (void)out_size; (void)ws_size;
  const float* X   = (const float*)d_in[0];
  const int*   tok = (const int*)d_in[1];
  const float* Wg  = (const float*)d_in[2];
  const float* Wu  = (const float*)d_in[3];
  const float* Wd  = (const float*)d_in[4];
  float* Out = (float*)d_out;

  char* ws = (char*)d_ws;
  int* meta  = (int*)ws;                       // 16 ints
  int* tlist = (int*)(ws + 64);                // up to ~68 tiles
  int* eid   = (int*)(ws + 2048);              // 16384 ints
  int* perm  = (int*)(ws + 2048 + 65536);      // 16384 ints
  int* inv   = (int*)(ws + 2048 + 131072);     // 16384 ints
  unsigned short* Wbf  = (unsigned short*)(ws + 262144);
  unsigned short* WgBf = Wbf;
  unsigned short* WuBf = Wbf + SLICE;
  unsigned short* WdBf = Wbf + 2 * SLICE;
  unsigned short* Xs   = Wbf + 3 * SLICE;      // expert-sorted bf16 X (2 slices)
  unsigned short* Hb   = Wbf + 5 * SLICE;      // NTOK*FF
  // total ws use: 262144 + 5*33554432 + 67108864 = 235,143,168 bytes (~224 MiB)

  k_init   <<<1, 64, 0, stream>>>(meta);
  k_assign <<<NTOK / 256, 256, 0, stream>>>(tok, eid, meta);
  k_prefix <<<1, 64, 0, stream>>>(meta, tlist);
  k_scatter<<<NTOK / 256, 256, 0, stream>>>(eid, meta, perm, inv);
  k_cast5  <<<dim3((unsigned)(SLICE / 2048), 5), 256, 0, stream>>>(Wg, Wu, Wd, X, inv, Wbf);
  k_gemm1  <<<dim3(16, NYT), 512, 0, stream>>>(Xs, WgBf, WuBf, meta, tlist, Hb);
  k_gemm2  <<<dim3(8, NYT), 512, 0, stream>>>(Hb, WdBf, meta, perm, tlist, Out);
}